// Round 3
// baseline (438.693 us; speedup 1.0000x reference)
//
#include <hip/hip_runtime.h>

typedef short bf16x8_t __attribute__((ext_vector_type(8)));
typedef float f32x4_t __attribute__((ext_vector_type(4)));

#define B_DIM 4096
#define Q_DIM 256
#define D_DIM 512
#define H_DIM 1024
#define O_DIM 512
#define E_NUM 16
#define K_TOP 4

#define BM 128
#define BN 128
#define BK 32

__device__ __forceinline__ short f2bf(float f) {
  unsigned int u = __float_as_uint(f);
  u += 0x7FFFu + ((u >> 16) & 1u);  // round-to-nearest-even
  return (short)(u >> 16);
}

// async global->LDS, 16B per lane. LDS dest must be wave-uniform base; lane i
// lands at base + i*16. Built via integer casts so the addrspace conversion
// always compiles (generic LDS ptr low 32 bits == LDS offset on gfx9+).
__device__ __forceinline__ void g2l16(const void* g, void* l) {
  __builtin_amdgcn_global_load_lds(
      (const __attribute__((address_space(1))) void*)(unsigned long long)(size_t)g,
      (__attribute__((address_space(3))) void*)(unsigned)(size_t)l, 16, 0, 0);
}

// ---------------- prep: x fp32 -> bf16, and gate-weight transposes (fp32)
__global__ __launch_bounds__(256) void prep_kernel(const float* __restrict__ x,
                                                   const float* __restrict__ wg,
                                                   const float* __restrict__ tg,
                                                   short* __restrict__ x_bf,
                                                   float* __restrict__ wgT,
                                                   float* __restrict__ tgT) {
  const int blk = blockIdx.x, t = threadIdx.x;
  if (blk < 1024) {  // x convert: 2048 floats/block
    int base = blk * 2048 + t * 8;
    float4 f0 = *(const float4*)(x + base);
    float4 f1 = *(const float4*)(x + base + 4);
    bf16x8_t v;
    v[0] = f2bf(f0.x); v[1] = f2bf(f0.y); v[2] = f2bf(f0.z); v[3] = f2bf(f0.w);
    v[4] = f2bf(f1.x); v[5] = f2bf(f1.y); v[6] = f2bf(f1.z); v[7] = f2bf(f1.w);
    *(bf16x8_t*)(x_bf + base) = v;
  } else {  // gate transposes: 12288 elems over 48 blocks
    int lin = (blk - 1024) * 256 + t;
    if (lin < D_DIM * E_NUM) {
      int e = lin / D_DIM, d = lin % D_DIM;
      wgT[lin] = wg[d * E_NUM + e];
    } else {
      int l2 = lin - D_DIM * E_NUM;
      int e = l2 / Q_DIM, q = l2 % Q_DIM;
      tgT[l2] = tg[q * E_NUM + e];
    }
  }
}

// ---------------- transpose + fp32->bf16 convert: src [E][R][C] f32 -> dst [E][C][R] bf16
__global__ __launch_bounds__(256) void transpose_cvt(const float* __restrict__ src,
                                                     short* __restrict__ dst, int R, int C) {
  __shared__ float tile[64][65];
  const int e = blockIdx.z;
  const int r0 = blockIdx.y * 64, c0 = blockIdx.x * 64;
  const int t = threadIdx.x;
  const float* s = src + (size_t)e * R * C;
  short* d = dst + (size_t)e * R * C;
#pragma unroll
  for (int i = 0; i < 16; i++) {
    int lin = i * 256 + t;
    int rr = lin >> 6, cc = lin & 63;
    tile[rr][cc] = s[(size_t)(r0 + rr) * C + (c0 + cc)];
  }
  __syncthreads();
#pragma unroll
  for (int i = 0; i < 16; i++) {
    int lin = i * 256 + t;
    int cr = lin >> 6, rc = lin & 63;
    d[(size_t)(c0 + cr) * R + (r0 + rc)] = f2bf(tile[rc][cr]);
  }
}

// ---------------- gating v4: 1 row/wave, lane = (chunk c<<4)|expert e, fp32 split-K.
__global__ __launch_bounds__(256) void gating_kernel(
    const float* __restrict__ x, const float* __restrict__ query,
    const float* __restrict__ wgT, const float* __restrict__ tgT,
    int* __restrict__ count, float* __restrict__ imp_g,
    int* __restrict__ rowlist, float* __restrict__ egate) {
  __shared__ float s_imp[E_NUM];
  const int t = threadIdx.x, wv = t >> 6, lane = t & 63;
  if (t < E_NUM) s_imp[t] = 0.f;
  __syncthreads();
  const int row = blockIdx.x * 4 + wv;
  const int e = lane & 15, c = lane >> 4;
  const float* xr = x + (size_t)row * D_DIM + c * 128;
  const float* qr = query + (size_t)row * Q_DIM + c * 64;
  const float* wr = wgT + e * D_DIM + c * 128;
  const float* tr = tgT + e * Q_DIM + c * 64;
  float a0 = 0.f, a1 = 0.f, a2 = 0.f, a3 = 0.f;
#pragma unroll 8
  for (int i = 0; i < 32; i++) {
    float4 xv = *(const float4*)(xr + i * 4);
    float4 wv4 = *(const float4*)(wr + i * 4);
    a0 += xv.x * wv4.x; a1 += xv.y * wv4.y;
    a2 += xv.z * wv4.z; a3 += xv.w * wv4.w;
  }
#pragma unroll 8
  for (int i = 0; i < 16; i++) {
    float4 xv = *(const float4*)(qr + i * 4);
    float4 wv4 = *(const float4*)(tr + i * 4);
    a0 += xv.x * wv4.x; a1 += xv.y * wv4.y;
    a2 += xv.z * wv4.z; a3 += xv.w * wv4.w;
  }
  float s = (a0 + a2) + (a1 + a3);
  s += __shfl_xor(s, 16, 64);
  s += __shfl_xor(s, 32, 64);  // every lane: logit for expert (lane&15)
  float v[E_NUM];
#pragma unroll
  for (int i = 0; i < E_NUM; i++) v[i] = __shfl(s, i, 64);
  if (lane == 0) {
    int idx[K_TOP];
    float val[K_TOP];
    unsigned used = 0;
    for (int k = 0; k < K_TOP; k++) {  // strict '>' => lowest index wins ties
      float best = -3.4e38f;
      int bi = 0;
      for (int i = 0; i < E_NUM; i++)
        if (!(used & (1u << i)) && v[i] > best) { best = v[i]; bi = i; }
      used |= 1u << bi;
      idx[k] = bi;
      val[k] = best;
    }
    float mx = val[0];
    float ex[K_TOP], Z = 0.f;
    for (int k = 0; k < K_TOP; k++) { ex[k] = __expf(val[k] - mx); Z += ex[k]; }
    for (int k = 0; k < K_TOP; k++) {
      float g = ex[k] / Z;
      int ee = idx[k];
      int pos = atomicAdd(&count[ee], 1);
      rowlist[ee * B_DIM + pos] = row;
      egate[ee * B_DIM + pos] = g;
      atomicAdd(&s_imp[ee], g);
    }
  }
  __syncthreads();
  if (t < E_NUM) atomicAdd(&imp_g[t], s_imp[t]);
}

// ---------------- loss (cv^2 ddof=1) + per-expert prefix offsets
__global__ __launch_bounds__(64) void loss_offsets_kernel(
    const int* __restrict__ count, const float* __restrict__ imp_g,
    int* __restrict__ offs, float* __restrict__ out_loss) {
  if (threadIdx.x == 0) {
    float mi = 0.f, ml = 0.f;
    for (int i = 0; i < E_NUM; i++) { mi += imp_g[i]; ml += (float)count[i]; }
    mi /= (float)E_NUM;
    ml /= (float)E_NUM;
    float vi = 0.f, vl = 0.f;
    for (int i = 0; i < E_NUM; i++) {
      float di = imp_g[i] - mi;
      vi += di * di;
      float dl = (float)count[i] - ml;
      vl += dl * dl;
    }
    vi /= (float)(E_NUM - 1);
    vl /= (float)(E_NUM - 1);
    out_loss[0] = 0.01f * (vi / (mi * mi + 1e-10f) + vl / (ml * ml + 1e-10f));
    int run = 0;
    for (int i = 0; i < E_NUM; i++) { offs[i] = run; run += count[i]; }
  }
}

// ---------------- GEMM1: h[entry] = relu(x[row] @ W1[e] + b1[e]), bf16 out
// m97 structure: global_load_lds width-16 staging into unpadded [128][32] tiles.
__global__ __launch_bounds__(256) void gemm1_kernel(
    const short* __restrict__ x_bf, const short* __restrict__ w1t,
    const float* __restrict__ b1, const int* __restrict__ count,
    const int* __restrict__ offs, const int* __restrict__ rowlist,
    short* __restrict__ h_buf) {
  const int e = blockIdx.z, mt = blockIdx.y, nt = blockIdx.x;
  const int n_e = count[e];
  if (mt * BM >= n_e) return;
  __shared__ __align__(16) short As[BM * BK];
  __shared__ __align__(16) short Bs[BN * BK];
  const int t = threadIdx.x, lane = t & 63, wv = t >> 6;
  const int wm = wv >> 1, wn = wv & 1;
  const int srow = wv * 16 + (lane >> 2);  // staging row 0..63
  const int kb = (lane & 3) * 8;           // bf16 elems within 32-elem k-slice
  int gr0 = mt * BM + srow;       gr0 = gr0 < n_e ? gr0 : n_e - 1;
  int gr1 = mt * BM + 64 + srow;  gr1 = gr1 < n_e ? gr1 : n_e - 1;
  const short* pa0 = x_bf + (size_t)rowlist[e * B_DIM + gr0] * D_DIM + kb;
  const short* pa1 = x_bf + (size_t)rowlist[e * B_DIM + gr1] * D_DIM + kb;
  const short* w1te = w1t + ((size_t)e * H_DIM + nt * BN) * D_DIM;
  const short* pb0 = w1te + (size_t)srow * D_DIM + kb;
  const short* pb1 = w1te + (size_t)(64 + srow) * D_DIM + kb;
  short* lA0 = As + wv * 16 * BK;
  short* lA1 = As + (64 + wv * 16) * BK;
  short* lB0 = Bs + wv * 16 * BK;
  short* lB1 = Bs + (64 + wv * 16) * BK;

  f32x4_t acc[4][4] = {};
  const int frow = lane & 15, kg = lane >> 4;

  for (int k0 = 0; k0 < D_DIM; k0 += BK) {
    g2l16(pa0 + k0, lA0);
    g2l16(pa1 + k0, lA1);
    g2l16(pb0 + k0, lB0);
    g2l16(pb1 + k0, lB1);
    __syncthreads();
    bf16x8_t af[4], bfr[4];
#pragma unroll
    for (int mi = 0; mi < 4; mi++)
      af[mi] = *(const bf16x8_t*)&As[(wm * 64 + mi * 16 + frow) * BK + kg * 8];
#pragma unroll
    for (int ni = 0; ni < 4; ni++)
      bfr[ni] = *(const bf16x8_t*)&Bs[(wn * 64 + ni * 16 + frow) * BK + kg * 8];
#pragma unroll
    for (int mi = 0; mi < 4; mi++)
#pragma unroll
      for (int ni = 0; ni < 4; ni++)
        acc[mi][ni] = __builtin_amdgcn_mfma_f32_16x16x32_bf16(af[mi], bfr[ni], acc[mi][ni], 0, 0, 0);
    __syncthreads();
  }
  const int obase = offs[e];
#pragma unroll
  for (int mi = 0; mi < 4; mi++) {
#pragma unroll
    for (int r = 0; r < 4; r++) {
      int row = wm * 64 + mi * 16 + kg * 4 + r;
      int m_local = mt * BM + row;
      if (m_local >= n_e) continue;
      size_t hrow = (size_t)(obase + m_local) * H_DIM;
#pragma unroll
      for (int ni = 0; ni < 4; ni++) {
        int col = nt * BN + wn * 64 + ni * 16 + frow;
        float vv = acc[mi][ni][r] + b1[e * H_DIM + col];
        h_buf[hrow + col] = f2bf(vv > 0.f ? vv : 0.f);
      }
    }
  }
}

// ---------------- GEMM2: y[row] += (h[entry] @ W2[e] + b2[e]) * gate (atomic)
__global__ __launch_bounds__(256) void gemm2_kernel(
    const short* __restrict__ h_buf, const short* __restrict__ w2t,
    const float* __restrict__ b2, const int* __restrict__ count,
    const int* __restrict__ offs, const int* __restrict__ rowlist,
    const float* __restrict__ egate, float* __restrict__ y) {
  const int e = blockIdx.z, mt = blockIdx.y, nt = blockIdx.x;
  const int n_e = count[e];
  if (mt * BM >= n_e) return;
  __shared__ __align__(16) short As[BM * BK];
  __shared__ __align__(16) short Bs[BN * BK];
  const int t = threadIdx.x, lane = t & 63, wv = t >> 6;
  const int wm = wv >> 1, wn = wv & 1;
  const int srow = wv * 16 + (lane >> 2);
  const int kb = (lane & 3) * 8;
  const int obase = offs[e];
  int gr0 = mt * BM + srow;       gr0 = gr0 < n_e ? gr0 : n_e - 1;
  int gr1 = mt * BM + 64 + srow;  gr1 = gr1 < n_e ? gr1 : n_e - 1;
  const short* pa0 = h_buf + (size_t)(obase + gr0) * H_DIM + kb;
  const short* pa1 = h_buf + (size_t)(obase + gr1) * H_DIM + kb;
  const short* w2te = w2t + ((size_t)e * O_DIM + nt * BN) * H_DIM;
  const short* pb0 = w2te + (size_t)srow * H_DIM + kb;
  const short* pb1 = w2te + (size_t)(64 + srow) * H_DIM + kb;
  short* lA0 = As + wv * 16 * BK;
  short* lA1 = As + (64 + wv * 16) * BK;
  short* lB0 = Bs + wv * 16 * BK;
  short* lB1 = Bs + (64 + wv * 16) * BK;

  f32x4_t acc[4][4] = {};
  const int frow = lane & 15, kg = lane >> 4;

  for (int k0 = 0; k0 < H_DIM; k0 += BK) {
    g2l16(pa0 + k0, lA0);
    g2l16(pa1 + k0, lA1);
    g2l16(pb0 + k0, lB0);
    g2l16(pb1 + k0, lB1);
    __syncthreads();
    bf16x8_t af[4], bfr[4];
#pragma unroll
    for (int mi = 0; mi < 4; mi++)
      af[mi] = *(const bf16x8_t*)&As[(wm * 64 + mi * 16 + frow) * BK + kg * 8];
#pragma unroll
    for (int ni = 0; ni < 4; ni++)
      bfr[ni] = *(const bf16x8_t*)&Bs[(wn * 64 + ni * 16 + frow) * BK + kg * 8];
#pragma unroll
    for (int mi = 0; mi < 4; mi++)
#pragma unroll
      for (int ni = 0; ni < 4; ni++)
        acc[mi][ni] = __builtin_amdgcn_mfma_f32_16x16x32_bf16(af[mi], bfr[ni], acc[mi][ni], 0, 0, 0);
    __syncthreads();
  }
#pragma unroll
  for (int mi = 0; mi < 4; mi++) {
#pragma unroll
    for (int r = 0; r < 4; r++) {
      int row = wm * 64 + mi * 16 + kg * 4 + r;
      int m_local = mt * BM + row;
      if (m_local >= n_e) continue;
      float g = egate[e * B_DIM + m_local];
      size_t yrow = (size_t)rowlist[e * B_DIM + m_local] * O_DIM;
#pragma unroll
      for (int ni = 0; ni < 4; ni++) {
        int col = nt * BN + wn * 64 + ni * 16 + frow;
        atomicAdd(&y[yrow + col], (acc[mi][ni][r] + b2[e * O_DIM + col]) * g);
      }
    }
  }
}

extern "C" void kernel_launch(void* const* d_in, const int* in_sizes, int n_in,
                              void* d_out, int out_size, void* d_ws, size_t ws_size,
                              hipStream_t stream) {
  (void)in_sizes; (void)n_in; (void)out_size; (void)ws_size;
  const float* query = (const float*)d_in[0];
  const float* x = (const float*)d_in[1];
  const float* wg = (const float*)d_in[2];
  const float* tg = (const float*)d_in[3];
  const float* W1 = (const float*)d_in[4];
  const float* b1 = (const float*)d_in[5];
  const float* W2 = (const float*)d_in[6];
  const float* b2 = (const float*)d_in[7];
  float* y = (float*)d_out;

  char* ws = (char*)d_ws;
  int* count = (int*)(ws + 0);             // 64 B
  float* imp = (float*)(ws + 64);          // 64 B
  int* offs = (int*)(ws + 128);            // 64 B
  int* rowlist = (int*)(ws + 256);         // 256 KB
  float* egate = (float*)(ws + 262400);    // 256 KB
  float* wgT = (float*)(ws + 524544);      // 32 KB
  float* tgT = (float*)(ws + 557312);      // 16 KB
  short* x_bf = (short*)(ws + 573696);     // 4 MB bf16 [4096][512]
  short* w1t = (short*)(ws + 4768000);     // 16 MB bf16 [E][H][D]
  short* w2t = (short*)(ws + 21545216);    // 16 MB bf16 [E][O][H]
  short* h_buf = (short*)(ws + 38322432);  // 32 MB bf16 [16384][H]

  hipMemsetAsync(ws, 0, 192, stream);
  hipMemsetAsync(y, 0, (size_t)B_DIM * O_DIM * sizeof(float), stream);
  prep_kernel<<<dim3(1072), 256, 0, stream>>>(x, wg, tg, x_bf, wgT, tgT);
  transpose_cvt<<<dim3(H_DIM / 64, D_DIM / 64, E_NUM), 256, 0, stream>>>(W1, w1t, D_DIM, H_DIM);
  transpose_cvt<<<dim3(O_DIM / 64, H_DIM / 64, E_NUM), 256, 0, stream>>>(W2, w2t, H_DIM, O_DIM);
  gating_kernel<<<dim3(B_DIM / 4), 256, 0, stream>>>(x, query, wgT, tgT, count, imp,
                                                     rowlist, egate);
  loss_offsets_kernel<<<1, 64, 0, stream>>>(count, imp, offs, y + (size_t)B_DIM * O_DIM);
  gemm1_kernel<<<dim3(H_DIM / BN, B_DIM / BM, E_NUM), 256, 0, stream>>>(
      x_bf, w1t, b1, count, offs, rowlist, h_buf);
  gemm2_kernel<<<dim3(O_DIM / BN, B_DIM / BM, E_NUM), 256, 0, stream>>>(
      h_buf, w2t, b2, count, offs, rowlist, egate, y);
}

// Round 4
// 414.702 us; speedup vs baseline: 1.0579x; 1.0579x over previous
//
#include <hip/hip_runtime.h>

typedef short bf16x8_t __attribute__((ext_vector_type(8)));
typedef float f32x4_t __attribute__((ext_vector_type(4)));

#define B_DIM 4096
#define Q_DIM 256
#define D_DIM 512
#define H_DIM 1024
#define O_DIM 512
#define E_NUM 16
#define K_TOP 4

#define BM 128
#define BN 128
#define BK 32

__device__ __forceinline__ short f2bf(float f) {
  unsigned int u = __float_as_uint(f);
  u += 0x7FFFu + ((u >> 16) & 1u);  // round-to-nearest-even
  return (short)(u >> 16);
}

// async global->LDS, 16B per lane; LDS dest wave-uniform base, lane i -> base+i*16
__device__ __forceinline__ void g2l16(const void* g, void* l) {
  __builtin_amdgcn_global_load_lds(
      (const __attribute__((address_space(1))) void*)(unsigned long long)(size_t)g,
      (__attribute__((address_space(3))) void*)(unsigned)(size_t)l, 16, 0, 0);
}

// ---------------- prep: x fp32 -> bf16; pack gate weights: wpack[e][0..511]=wg[:,e],
// wpack[e][512..767]=tg[:,e]
__global__ __launch_bounds__(256) void prep_kernel(const float* __restrict__ x,
                                                   const float* __restrict__ wg,
                                                   const float* __restrict__ tg,
                                                   short* __restrict__ x_bf,
                                                   float* __restrict__ wpack) {
  const int blk = blockIdx.x, t = threadIdx.x;
  if (blk < 1024) {  // x convert: 2048 floats/block
    int base = blk * 2048 + t * 8;
    float4 f0 = *(const float4*)(x + base);
    float4 f1 = *(const float4*)(x + base + 4);
    bf16x8_t v;
    v[0] = f2bf(f0.x); v[1] = f2bf(f0.y); v[2] = f2bf(f0.z); v[3] = f2bf(f0.w);
    v[4] = f2bf(f1.x); v[5] = f2bf(f1.y); v[6] = f2bf(f1.z); v[7] = f2bf(f1.w);
    *(bf16x8_t*)(x_bf + base) = v;
  } else {  // pack: 12288 elems over 48 blocks
    int lin = (blk - 1024) * 256 + t;
    if (lin < E_NUM * 768) {
      int e = lin / 768, r = lin % 768;
      wpack[lin] = (r < D_DIM) ? wg[r * E_NUM + e] : tg[(r - D_DIM) * E_NUM + e];
    }
  }
}

// ---------------- transpose + fp32->bf16 convert: src [E][R][C] f32 -> dst [E][C][R] bf16
__global__ __launch_bounds__(256) void transpose_cvt(const float* __restrict__ src,
                                                     short* __restrict__ dst, int R, int C) {
  __shared__ float tile[64][65];
  const int e = blockIdx.z;
  const int r0 = blockIdx.y * 64, c0 = blockIdx.x * 64;
  const int t = threadIdx.x;
  const float* s = src + (size_t)e * R * C;
  short* d = dst + (size_t)e * R * C;
#pragma unroll
  for (int i = 0; i < 16; i++) {
    int lin = i * 256 + t;
    int rr = lin >> 6, cc = lin & 63;
    tile[rr][cc] = s[(size_t)(r0 + rr) * C + (c0 + cc)];
  }
  __syncthreads();
#pragma unroll
  for (int i = 0; i < 16; i++) {
    int lin = i * 256 + t;
    int cr = lin >> 6, rc = lin & 63;
    d[(size_t)(c0 + cr) * R + (r0 + rc)] = f2bf(tile[rc][cr]);
  }
}

// ---------------- gating v5: 1 row/wave; coalesced x/query float4 loads;
// LDS-staged packed weights, lane-consecutive b128 reads; butterfly reduce.
__global__ __launch_bounds__(256) void gating_kernel(
    const float* __restrict__ x, const float* __restrict__ query,
    const float* __restrict__ wpack,
    int* __restrict__ count, float* __restrict__ imp_g,
    int* __restrict__ rowlist, int* __restrict__ slotid, float* __restrict__ egate) {
  __shared__ __align__(16) float4 s_w[E_NUM * 192];  // 48 KB
  __shared__ float s_imp[E_NUM];
  const int t = threadIdx.x, wv = t >> 6, lane = t & 63;
  if (t < E_NUM) s_imp[t] = 0.f;
  const float4* wp4 = (const float4*)wpack;
#pragma unroll
  for (int i = 0; i < 12; i++) s_w[i * 256 + t] = wp4[i * 256 + t];
  __syncthreads();

  const int row = blockIdx.x * 4 + wv;
  const float4* xr = (const float4*)(x + (size_t)row * D_DIM);
  const float4* qr = (const float4*)(query + (size_t)row * Q_DIM);
  const float4 xv0 = xr[lane], xv1 = xr[64 + lane], qv = qr[lane];

  float p[E_NUM];
#pragma unroll
  for (int e = 0; e < E_NUM; e++) {
    float4 w0 = s_w[e * 192 + lane];
    float4 w1 = s_w[e * 192 + 64 + lane];
    float4 wq = s_w[e * 192 + 128 + lane];
    p[e] = xv0.x * w0.x + xv0.y * w0.y + xv0.z * w0.z + xv0.w * w0.w +
           xv1.x * w1.x + xv1.y * w1.y + xv1.z * w1.z + xv1.w * w1.w +
           qv.x * wq.x + qv.y * wq.y + qv.z * wq.z + qv.w * wq.w;
  }
  // lanes differing in bits 4,5: plain fold
#pragma unroll
  for (int e = 0; e < E_NUM; e++) {
    p[e] += __shfl_xor(p[e], 16, 64);
    p[e] += __shfl_xor(p[e], 32, 64);
  }
  // fold e-dimension over lane bits 3..0; after this, lane l holds e = l & 15
#pragma unroll
  for (int s = 8; s >= 1; s >>= 1) {
    const bool take = (lane & s) != 0;
#pragma unroll
    for (int j = 0; j < s; j++) {
      float keep = take ? p[j + s] : p[j];
      float send = take ? p[j] : p[j + s];
      p[j] = keep + __shfl_xor(send, s, 64);
    }
  }
  const float logit = p[0];
  float v[E_NUM];
#pragma unroll
  for (int i = 0; i < E_NUM; i++) v[i] = __shfl(logit, i, 64);

  if (lane == 0) {
    int idx[K_TOP];
    float val[K_TOP];
    unsigned used = 0;
    for (int k = 0; k < K_TOP; k++) {  // strict '>' => lowest index wins ties
      float best = -3.4e38f;
      int bi = 0;
      for (int i = 0; i < E_NUM; i++)
        if (!(used & (1u << i)) && v[i] > best) { best = v[i]; bi = i; }
      used |= 1u << bi;
      idx[k] = bi;
      val[k] = best;
    }
    float mx = val[0];
    float ex[K_TOP], Z = 0.f;
    for (int k = 0; k < K_TOP; k++) { ex[k] = __expf(val[k] - mx); Z += ex[k]; }
    for (int k = 0; k < K_TOP; k++) {
      float g = ex[k] / Z;
      int ee = idx[k];
      int pos = atomicAdd(&count[ee], 1);
      rowlist[ee * B_DIM + pos] = row;
      slotid[ee * B_DIM + pos] = row * K_TOP + k;
      egate[ee * B_DIM + pos] = g;
      atomicAdd(&s_imp[ee], g);
    }
  }
  __syncthreads();
  if (t < E_NUM) atomicAdd(&imp_g[t], s_imp[t]);
}

// ---------------- loss (cv^2 ddof=1) + per-expert prefix offsets
__global__ __launch_bounds__(64) void loss_offsets_kernel(
    const int* __restrict__ count, const float* __restrict__ imp_g,
    int* __restrict__ offs, float* __restrict__ out_loss) {
  if (threadIdx.x == 0) {
    float mi = 0.f, ml = 0.f;
    for (int i = 0; i < E_NUM; i++) { mi += imp_g[i]; ml += (float)count[i]; }
    mi /= (float)E_NUM;
    ml /= (float)E_NUM;
    float vi = 0.f, vl = 0.f;
    for (int i = 0; i < E_NUM; i++) {
      float di = imp_g[i] - mi;
      vi += di * di;
      float dl = (float)count[i] - ml;
      vl += dl * dl;
    }
    vi /= (float)(E_NUM - 1);
    vl /= (float)(E_NUM - 1);
    out_loss[0] = 0.01f * (vi / (mi * mi + 1e-10f) + vl / (ml * ml + 1e-10f));
    int run = 0;
    for (int i = 0; i < E_NUM; i++) { offs[i] = run; run += count[i]; }
  }
}

// ---------------- GEMM1: h[entry] = relu(x[row] @ W1[e] + b1[e]), bf16 out
__global__ __launch_bounds__(256) void gemm1_kernel(
    const short* __restrict__ x_bf, const short* __restrict__ w1t,
    const float* __restrict__ b1, const int* __restrict__ count,
    const int* __restrict__ offs, const int* __restrict__ rowlist,
    short* __restrict__ h_buf) {
  const int e = blockIdx.z, mt = blockIdx.y, nt = blockIdx.x;
  const int n_e = count[e];
  if (mt * BM >= n_e) return;
  __shared__ __align__(16) short As[BM * BK];
  __shared__ __align__(16) short Bs[BN * BK];
  const int t = threadIdx.x, lane = t & 63, wv = t >> 6;
  const int wm = wv >> 1, wn = wv & 1;
  const int srow = wv * 16 + (lane >> 2);  // staging row 0..63
  const int kb = (lane & 3) * 8;           // bf16 elems within 32-elem k-slice
  int gr0 = mt * BM + srow;       gr0 = gr0 < n_e ? gr0 : n_e - 1;
  int gr1 = mt * BM + 64 + srow;  gr1 = gr1 < n_e ? gr1 : n_e - 1;
  const short* pa0 = x_bf + (size_t)rowlist[e * B_DIM + gr0] * D_DIM + kb;
  const short* pa1 = x_bf + (size_t)rowlist[e * B_DIM + gr1] * D_DIM + kb;
  const short* w1te = w1t + ((size_t)e * H_DIM + nt * BN) * D_DIM;
  const short* pb0 = w1te + (size_t)srow * D_DIM + kb;
  const short* pb1 = w1te + (size_t)(64 + srow) * D_DIM + kb;
  short* lA0 = As + wv * 16 * BK;
  short* lA1 = As + (64 + wv * 16) * BK;
  short* lB0 = Bs + wv * 16 * BK;
  short* lB1 = Bs + (64 + wv * 16) * BK;

  f32x4_t acc[4][4] = {};
  const int frow = lane & 15, kg = lane >> 4;

  for (int k0 = 0; k0 < D_DIM; k0 += BK) {
    g2l16(pa0 + k0, lA0);
    g2l16(pa1 + k0, lA1);
    g2l16(pb0 + k0, lB0);
    g2l16(pb1 + k0, lB1);
    __syncthreads();
    bf16x8_t af[4], bfr[4];
#pragma unroll
    for (int mi = 0; mi < 4; mi++)
      af[mi] = *(const bf16x8_t*)&As[(wm * 64 + mi * 16 + frow) * BK + kg * 8];
#pragma unroll
    for (int ni = 0; ni < 4; ni++)
      bfr[ni] = *(const bf16x8_t*)&Bs[(wn * 64 + ni * 16 + frow) * BK + kg * 8];
#pragma unroll
    for (int mi = 0; mi < 4; mi++)
#pragma unroll
      for (int ni = 0; ni < 4; ni++)
        acc[mi][ni] = __builtin_amdgcn_mfma_f32_16x16x32_bf16(af[mi], bfr[ni], acc[mi][ni], 0, 0, 0);
    __syncthreads();
  }
  const int obase = offs[e];
#pragma unroll
  for (int mi = 0; mi < 4; mi++) {
#pragma unroll
    for (int r = 0; r < 4; r++) {
      int row = wm * 64 + mi * 16 + kg * 4 + r;
      int m_local = mt * BM + row;
      if (m_local >= n_e) continue;
      size_t hrow = (size_t)(obase + m_local) * H_DIM;
#pragma unroll
      for (int ni = 0; ni < 4; ni++) {
        int col = nt * BN + wn * 64 + ni * 16 + frow;
        float vv = acc[mi][ni][r] + b1[e * H_DIM + col];
        h_buf[hrow + col] = f2bf(vv > 0.f ? vv : 0.f);
      }
    }
  }
}

// ---------------- GEMM2: out_buf[slot] = (h[entry] @ W2[e] + b2[e]) * gate
__global__ __launch_bounds__(256) void gemm2_kernel(
    const short* __restrict__ h_buf, const short* __restrict__ w2t,
    const float* __restrict__ b2, const int* __restrict__ count,
    const int* __restrict__ offs, const int* __restrict__ slotid,
    const float* __restrict__ egate, float* __restrict__ out_buf) {
  const int e = blockIdx.z, mt = blockIdx.y, nt = blockIdx.x;
  const int n_e = count[e];
  if (mt * BM >= n_e) return;
  __shared__ __align__(16) short As[BM * BK];
  __shared__ __align__(16) short Bs[BN * BK];
  const int t = threadIdx.x, lane = t & 63, wv = t >> 6;
  const int wm = wv >> 1, wn = wv & 1;
  const int srow = wv * 16 + (lane >> 2);
  const int kb = (lane & 3) * 8;
  const int obase = offs[e];
  int gr0 = mt * BM + srow;       gr0 = gr0 < n_e ? gr0 : n_e - 1;
  int gr1 = mt * BM + 64 + srow;  gr1 = gr1 < n_e ? gr1 : n_e - 1;
  const short* pa0 = h_buf + (size_t)(obase + gr0) * H_DIM + kb;
  const short* pa1 = h_buf + (size_t)(obase + gr1) * H_DIM + kb;
  const short* w2te = w2t + ((size_t)e * O_DIM + nt * BN) * H_DIM;
  const short* pb0 = w2te + (size_t)srow * H_DIM + kb;
  const short* pb1 = w2te + (size_t)(64 + srow) * H_DIM + kb;
  short* lA0 = As + wv * 16 * BK;
  short* lA1 = As + (64 + wv * 16) * BK;
  short* lB0 = Bs + wv * 16 * BK;
  short* lB1 = Bs + (64 + wv * 16) * BK;

  f32x4_t acc[4][4] = {};
  const int frow = lane & 15, kg = lane >> 4;

  for (int k0 = 0; k0 < H_DIM; k0 += BK) {
    g2l16(pa0 + k0, lA0);
    g2l16(pa1 + k0, lA1);
    g2l16(pb0 + k0, lB0);
    g2l16(pb1 + k0, lB1);
    __syncthreads();
    bf16x8_t af[4], bfr[4];
#pragma unroll
    for (int mi = 0; mi < 4; mi++)
      af[mi] = *(const bf16x8_t*)&As[(wm * 64 + mi * 16 + frow) * BK + kg * 8];
#pragma unroll
    for (int ni = 0; ni < 4; ni++)
      bfr[ni] = *(const bf16x8_t*)&Bs[(wn * 64 + ni * 16 + frow) * BK + kg * 8];
#pragma unroll
    for (int mi = 0; mi < 4; mi++)
#pragma unroll
      for (int ni = 0; ni < 4; ni++)
        acc[mi][ni] = __builtin_amdgcn_mfma_f32_16x16x32_bf16(af[mi], bfr[ni], acc[mi][ni], 0, 0, 0);
    __syncthreads();
  }
#pragma unroll
  for (int mi = 0; mi < 4; mi++) {
#pragma unroll
    for (int r = 0; r < 4; r++) {
      int row = wm * 64 + mi * 16 + kg * 4 + r;
      int m_local = mt * BM + row;
      if (m_local >= n_e) continue;
      float g = egate[e * B_DIM + m_local];
      size_t orow = (size_t)slotid[e * B_DIM + m_local] * O_DIM;
#pragma unroll
      for (int ni = 0; ni < 4; ni++) {
        int col = nt * BN + wn * 64 + ni * 16 + frow;
        out_buf[orow + col] = (acc[mi][ni][r] + b2[e * O_DIM + col]) * g;
      }
    }
  }
}

// ---------------- combine: y[b] = sum over 4 slots
__global__ __launch_bounds__(256) void combine_kernel(const float* __restrict__ out_buf,
                                                      float* __restrict__ y) {
  int idx = blockIdx.x * 256 + threadIdx.x;  // B*O/4 threads
  int b = idx >> 7;
  int o = (idx & 127) << 2;
  const float* base = out_buf + (size_t)b * K_TOP * O_DIM + o;
  float4 a0 = *(const float4*)(base);
  float4 a1 = *(const float4*)(base + O_DIM);
  float4 a2 = *(const float4*)(base + 2 * O_DIM);
  float4 a3 = *(const float4*)(base + 3 * O_DIM);
  float4 r;
  r.x = a0.x + a1.x + a2.x + a3.x;
  r.y = a0.y + a1.y + a2.y + a3.y;
  r.z = a0.z + a1.z + a2.z + a3.z;
  r.w = a0.w + a1.w + a2.w + a3.w;
  *(float4*)(y + (size_t)b * O_DIM + o) = r;
}

extern "C" void kernel_launch(void* const* d_in, const int* in_sizes, int n_in,
                              void* d_out, int out_size, void* d_ws, size_t ws_size,
                              hipStream_t stream) {
  (void)in_sizes; (void)n_in; (void)out_size; (void)ws_size;
  const float* query = (const float*)d_in[0];
  const float* x = (const float*)d_in[1];
  const float* wg = (const float*)d_in[2];
  const float* tg = (const float*)d_in[3];
  const float* W1 = (const float*)d_in[4];
  const float* b1 = (const float*)d_in[5];
  const float* W2 = (const float*)d_in[6];
  const float* b2 = (const float*)d_in[7];
  float* y = (float*)d_out;

  char* ws = (char*)d_ws;
  int* count = (int*)(ws + 0);               // 64 B
  float* imp = (float*)(ws + 64);            // 64 B
  int* offs = (int*)(ws + 128);              // 64 B
  int* rowlist = (int*)(ws + 256);           // 256 KB
  int* slotid = (int*)(ws + 262400);         // 256 KB
  float* egate = (float*)(ws + 524544);      // 256 KB
  short* h_buf = (short*)(ws + 786688);      // 32 MB bf16 [16384][H]  (live gemm1->gemm2)
  short* w2t = (short*)(ws + 34341120);      // 16 MB bf16 [E][O][H]   (live ->gemm2)
  // region A: early-phase buffers, overlaid by out_buf in gemm2/combine
  short* x_bf = (short*)(ws + 51118336);     // 4 MB  bf16 [4096][512] (dead after gemm1)
  short* w1t = (short*)(ws + 55312640);      // 16 MB bf16 [E][H][D]   (dead after gemm1)
  float* wpack = (float*)(ws + 72089856);    // 48 KB                  (dead after gating)
  float* out_buf = (float*)(ws + 51118336);  // 32 MB f32 [16384][O]   (overlays region A)

  hipMemsetAsync(ws, 0, 192, stream);
  prep_kernel<<<dim3(1072), 256, 0, stream>>>(x, wg, tg, x_bf, wpack);
  transpose_cvt<<<dim3(H_DIM / 64, D_DIM / 64, E_NUM), 256, 0, stream>>>(W1, w1t, D_DIM, H_DIM);
  transpose_cvt<<<dim3(O_DIM / 64, H_DIM / 64, E_NUM), 256, 0, stream>>>(W2, w2t, H_DIM, O_DIM);
  gating_kernel<<<dim3(B_DIM / 4), 256, 0, stream>>>(x, query, wpack, count, imp,
                                                     rowlist, slotid, egate);
  loss_offsets_kernel<<<1, 64, 0, stream>>>(count, imp, offs, y + (size_t)B_DIM * O_DIM);
  gemm1_kernel<<<dim3(H_DIM / BN, B_DIM / BM, E_NUM), 256, 0, stream>>>(
      x_bf, w1t, b1, count, offs, rowlist, h_buf);
  gemm2_kernel<<<dim3(O_DIM / BN, B_DIM / BM, E_NUM), 256, 0, stream>>>(
      h_buf, w2t, b2, count, offs, slotid, egate, out_buf);
  combine_kernel<<<dim3(B_DIM * O_DIM / 4 / 256), 256, 0, stream>>>(out_buf, y);
}

// Round 5
// 251.492 us; speedup vs baseline: 1.7444x; 1.6490x over previous
//
#include <hip/hip_runtime.h>

typedef short bf16x8_t __attribute__((ext_vector_type(8)));
typedef float f32x4_t __attribute__((ext_vector_type(4)));

#define B_DIM 4096
#define Q_DIM 256
#define D_DIM 512
#define H_DIM 1024
#define O_DIM 512
#define E_NUM 16
#define K_TOP 4

#define BM 128
#define BN 128
#define BK 32

__device__ __forceinline__ short f2bf(float f) {
  unsigned int u = __float_as_uint(f);
  u += 0x7FFFu + ((u >> 16) & 1u);  // round-to-nearest-even
  return (short)(u >> 16);
}

// async global->LDS, 16B per lane; LDS dest wave-uniform base, lane i -> base+i*16
__device__ __forceinline__ void g2l16(const void* g, void* l) {
  __builtin_amdgcn_global_load_lds(
      (const __attribute__((address_space(1))) void*)(unsigned long long)(size_t)g,
      (__attribute__((address_space(3))) void*)(unsigned)(size_t)l, 16, 0, 0);
}

// ---------------- prep: x fp32 -> bf16; pack gate weights: wpack[e][0..511]=wg[:,e],
// wpack[e][512..767]=tg[:,e]
__global__ __launch_bounds__(256) void prep_kernel(const float* __restrict__ x,
                                                   const float* __restrict__ wg,
                                                   const float* __restrict__ tg,
                                                   short* __restrict__ x_bf,
                                                   float* __restrict__ wpack) {
  const int blk = blockIdx.x, t = threadIdx.x;
  if (blk < 1024) {  // x convert: 2048 floats/block
    int base = blk * 2048 + t * 8;
    float4 f0 = *(const float4*)(x + base);
    float4 f1 = *(const float4*)(x + base + 4);
    bf16x8_t v;
    v[0] = f2bf(f0.x); v[1] = f2bf(f0.y); v[2] = f2bf(f0.z); v[3] = f2bf(f0.w);
    v[4] = f2bf(f1.x); v[5] = f2bf(f1.y); v[6] = f2bf(f1.z); v[7] = f2bf(f1.w);
    *(bf16x8_t*)(x_bf + base) = v;
  } else {  // pack: 12288 elems over 48 blocks
    int lin = (blk - 1024) * 256 + t;
    if (lin < E_NUM * 768) {
      int e = lin / 768, r = lin % 768;
      wpack[lin] = (r < D_DIM) ? wg[r * E_NUM + e] : tg[(r - D_DIM) * E_NUM + e];
    }
  }
}

// ---------------- transpose + fp32->bf16 convert: src [E][R][C] f32 -> dst [E][C][R] bf16
__global__ __launch_bounds__(256) void transpose_cvt(const float* __restrict__ src,
                                                     short* __restrict__ dst, int R, int C) {
  __shared__ float tile[64][65];
  const int e = blockIdx.z;
  const int r0 = blockIdx.y * 64, c0 = blockIdx.x * 64;
  const int t = threadIdx.x;
  const float* s = src + (size_t)e * R * C;
  short* d = dst + (size_t)e * R * C;
#pragma unroll
  for (int i = 0; i < 16; i++) {
    int lin = i * 256 + t;
    int rr = lin >> 6, cc = lin & 63;
    tile[rr][cc] = s[(size_t)(r0 + rr) * C + (c0 + cc)];
  }
  __syncthreads();
#pragma unroll
  for (int i = 0; i < 16; i++) {
    int lin = i * 256 + t;
    int cr = lin >> 6, rc = lin & 63;
    d[(size_t)(c0 + cr) * R + (r0 + rc)] = f2bf(tile[rc][cr]);
  }
}

// ---------------- gating v6: 1 row/wave; coalesced float4 loads; LDS weights;
// butterfly reduce; lane0 top-4 + softmax -> per-row arrays. NO ATOMICS.
__global__ __launch_bounds__(256) void gating_kernel(
    const float* __restrict__ x, const float* __restrict__ query,
    const float* __restrict__ wpack,
    int4* __restrict__ topk_e4, float4* __restrict__ topk_g4) {
  __shared__ __align__(16) float4 s_w[E_NUM * 192];  // 48 KB
  const int t = threadIdx.x, wv = t >> 6, lane = t & 63;
  const float4* wp4 = (const float4*)wpack;
#pragma unroll
  for (int i = 0; i < 12; i++) s_w[i * 256 + t] = wp4[i * 256 + t];
  __syncthreads();

  const int row = blockIdx.x * 4 + wv;
  const float4* xr = (const float4*)(x + (size_t)row * D_DIM);
  const float4* qr = (const float4*)(query + (size_t)row * Q_DIM);
  const float4 xv0 = xr[lane], xv1 = xr[64 + lane], qv = qr[lane];

  float p[E_NUM];
#pragma unroll
  for (int e = 0; e < E_NUM; e++) {
    float4 w0 = s_w[e * 192 + lane];
    float4 w1 = s_w[e * 192 + 64 + lane];
    float4 wq = s_w[e * 192 + 128 + lane];
    p[e] = xv0.x * w0.x + xv0.y * w0.y + xv0.z * w0.z + xv0.w * w0.w +
           xv1.x * w1.x + xv1.y * w1.y + xv1.z * w1.z + xv1.w * w1.w +
           qv.x * wq.x + qv.y * wq.y + qv.z * wq.z + qv.w * wq.w;
  }
#pragma unroll
  for (int e = 0; e < E_NUM; e++) {
    p[e] += __shfl_xor(p[e], 16, 64);
    p[e] += __shfl_xor(p[e], 32, 64);
  }
  // fold e-dimension over lane bits 3..0; after this, lane l holds e = l & 15
#pragma unroll
  for (int s = 8; s >= 1; s >>= 1) {
    const bool take = (lane & s) != 0;
#pragma unroll
    for (int j = 0; j < s; j++) {
      float keep = take ? p[j + s] : p[j];
      float send = take ? p[j] : p[j + s];
      p[j] = keep + __shfl_xor(send, s, 64);
    }
  }
  const float logit = p[0];
  float v[E_NUM];
#pragma unroll
  for (int i = 0; i < E_NUM; i++) v[i] = __shfl(logit, i, 64);

  if (lane == 0) {
    int idx[K_TOP];
    float val[K_TOP];
    unsigned used = 0;
    for (int k = 0; k < K_TOP; k++) {  // strict '>' => lowest index wins ties
      float best = -3.4e38f;
      int bi = 0;
      for (int i = 0; i < E_NUM; i++)
        if (!(used & (1u << i)) && v[i] > best) { best = v[i]; bi = i; }
      used |= 1u << bi;
      idx[k] = bi;
      val[k] = best;
    }
    float mx = val[0];
    float ex[K_TOP], Z = 0.f;
    for (int k = 0; k < K_TOP; k++) { ex[k] = __expf(val[k] - mx); Z += ex[k]; }
    topk_e4[row] = make_int4(idx[0], idx[1], idx[2], idx[3]);
    topk_g4[row] = make_float4(ex[0] / Z, ex[1] / Z, ex[2] / Z, ex[3] / Z);
  }
}

// ---------------- CSR build: 1 block per expert, deterministic prefix-scan positions.
// Writes count[e], imp[e], and the per-expert row/slot/gate lists. NO ATOMICS.
__global__ __launch_bounds__(256) void csr_kernel(
    const int4* __restrict__ topk_e4, const float4* __restrict__ topk_g4,
    int* __restrict__ count, float* __restrict__ imp_g,
    int* __restrict__ rowlist, int* __restrict__ slotid, float* __restrict__ egate) {
  const int e = blockIdx.x, t = threadIdx.x;
  __shared__ int s_cnt[256];
  __shared__ float s_gs[64];
  // pass 1: count matches + gate sum over this thread's 16 rows
  int c = 0;
  float gs = 0.f;
#pragma unroll 4
  for (int i = 0; i < 16; i++) {
    int row = t * 16 + i;
    int4 v = topk_e4[row];
    float4 g = topk_g4[row];
    if (v.x == e) { c++; gs += g.x; }
    if (v.y == e) { c++; gs += g.y; }
    if (v.z == e) { c++; gs += g.z; }
    if (v.w == e) { c++; gs += g.w; }
  }
  s_cnt[t] = c;
  // wave-reduce gate sum, one LDS slot per wave
  float gw = gs;
  for (int off = 32; off >= 1; off >>= 1) gw += __shfl_down(gw, off, 64);
  if ((t & 63) == 0) s_gs[t >> 6] = gw;
  __syncthreads();
  // Hillis-Steele inclusive scan over 256 thread counts
  for (int off = 1; off < 256; off <<= 1) {
    int vv = (t >= off) ? s_cnt[t - off] : 0;
    __syncthreads();
    s_cnt[t] += vv;
    __syncthreads();
  }
  int pos = s_cnt[t] - c;  // exclusive base for this thread
  // pass 2: emit entries in row order
#pragma unroll 4
  for (int i = 0; i < 16; i++) {
    int row = t * 16 + i;
    int4 v = topk_e4[row];
    float4 g = topk_g4[row];
    int ve[4] = {v.x, v.y, v.z, v.w};
    float vg[4] = {g.x, g.y, g.z, g.w};
#pragma unroll
    for (int k = 0; k < K_TOP; k++) {
      if (ve[k] == e) {
        rowlist[e * B_DIM + pos] = row;
        slotid[e * B_DIM + pos] = row * K_TOP + k;
        egate[e * B_DIM + pos] = vg[k];
        pos++;
      }
    }
  }
  if (t == 0) {
    count[e] = s_cnt[255];
    imp_g[e] = s_gs[0] + s_gs[1] + s_gs[2] + s_gs[3];
  }
}

// ---------------- loss (cv^2 ddof=1) + per-expert prefix offsets
__global__ __launch_bounds__(64) void loss_offsets_kernel(
    const int* __restrict__ count, const float* __restrict__ imp_g,
    int* __restrict__ offs, float* __restrict__ out_loss) {
  if (threadIdx.x == 0) {
    float mi = 0.f, ml = 0.f;
    for (int i = 0; i < E_NUM; i++) { mi += imp_g[i]; ml += (float)count[i]; }
    mi /= (float)E_NUM;
    ml /= (float)E_NUM;
    float vi = 0.f, vl = 0.f;
    for (int i = 0; i < E_NUM; i++) {
      float di = imp_g[i] - mi;
      vi += di * di;
      float dl = (float)count[i] - ml;
      vl += dl * dl;
    }
    vi /= (float)(E_NUM - 1);
    vl /= (float)(E_NUM - 1);
    out_loss[0] = 0.01f * (vi / (mi * mi + 1e-10f) + vl / (ml * ml + 1e-10f));
    int run = 0;
    for (int i = 0; i < E_NUM; i++) { offs[i] = run; run += count[i]; }
  }
}

// ---------------- GEMM1: h[entry] = relu(x[row] @ W1[e] + b1[e]), bf16 out
__global__ __launch_bounds__(256) void gemm1_kernel(
    const short* __restrict__ x_bf, const short* __restrict__ w1t,
    const float* __restrict__ b1, const int* __restrict__ count,
    const int* __restrict__ offs, const int* __restrict__ rowlist,
    short* __restrict__ h_buf) {
  const int e = blockIdx.z, mt = blockIdx.y, nt = blockIdx.x;
  const int n_e = count[e];
  if (mt * BM >= n_e) return;
  __shared__ __align__(16) short As[BM * BK];
  __shared__ __align__(16) short Bs[BN * BK];
  const int t = threadIdx.x, lane = t & 63, wv = t >> 6;
  const int wm = wv >> 1, wn = wv & 1;
  const int srow = wv * 16 + (lane >> 2);  // staging row 0..63
  const int kb = (lane & 3) * 8;           // bf16 elems within 32-elem k-slice
  int gr0 = mt * BM + srow;       gr0 = gr0 < n_e ? gr0 : n_e - 1;
  int gr1 = mt * BM + 64 + srow;  gr1 = gr1 < n_e ? gr1 : n_e - 1;
  const short* pa0 = x_bf + (size_t)rowlist[e * B_DIM + gr0] * D_DIM + kb;
  const short* pa1 = x_bf + (size_t)rowlist[e * B_DIM + gr1] * D_DIM + kb;
  const short* w1te = w1t + ((size_t)e * H_DIM + nt * BN) * D_DIM;
  const short* pb0 = w1te + (size_t)srow * D_DIM + kb;
  const short* pb1 = w1te + (size_t)(64 + srow) * D_DIM + kb;
  short* lA0 = As + wv * 16 * BK;
  short* lA1 = As + (64 + wv * 16) * BK;
  short* lB0 = Bs + wv * 16 * BK;
  short* lB1 = Bs + (64 + wv * 16) * BK;

  f32x4_t acc[4][4] = {};
  const int frow = lane & 15, kg = lane >> 4;

  for (int k0 = 0; k0 < D_DIM; k0 += BK) {
    g2l16(pa0 + k0, lA0);
    g2l16(pa1 + k0, lA1);
    g2l16(pb0 + k0, lB0);
    g2l16(pb1 + k0, lB1);
    __syncthreads();
    bf16x8_t af[4], bfr[4];
#pragma unroll
    for (int mi = 0; mi < 4; mi++)
      af[mi] = *(const bf16x8_t*)&As[(wm * 64 + mi * 16 + frow) * BK + kg * 8];
#pragma unroll
    for (int ni = 0; ni < 4; ni++)
      bfr[ni] = *(const bf16x8_t*)&Bs[(wn * 64 + ni * 16 + frow) * BK + kg * 8];
#pragma unroll
    for (int mi = 0; mi < 4; mi++)
#pragma unroll
      for (int ni = 0; ni < 4; ni++)
        acc[mi][ni] = __builtin_amdgcn_mfma_f32_16x16x32_bf16(af[mi], bfr[ni], acc[mi][ni], 0, 0, 0);
    __syncthreads();
  }
  const int obase = offs[e];
#pragma unroll
  for (int mi = 0; mi < 4; mi++) {
#pragma unroll
    for (int r = 0; r < 4; r++) {
      int row = wm * 64 + mi * 16 + kg * 4 + r;
      int m_local = mt * BM + row;
      if (m_local >= n_e) continue;
      size_t hrow = (size_t)(obase + m_local) * H_DIM;
#pragma unroll
      for (int ni = 0; ni < 4; ni++) {
        int col = nt * BN + wn * 64 + ni * 16 + frow;
        float vv = acc[mi][ni][r] + b1[e * H_DIM + col];
        h_buf[hrow + col] = f2bf(vv > 0.f ? vv : 0.f);
      }
    }
  }
}

// ---------------- GEMM2: out_buf[slot] = (h[entry] @ W2[e] + b2[e]) * gate
__global__ __launch_bounds__(256) void gemm2_kernel(
    const short* __restrict__ h_buf, const short* __restrict__ w2t,
    const float* __restrict__ b2, const int* __restrict__ count,
    const int* __restrict__ offs, const int* __restrict__ slotid,
    const float* __restrict__ egate, float* __restrict__ out_buf) {
  const int e = blockIdx.z, mt = blockIdx.y, nt = blockIdx.x;
  const int n_e = count[e];
  if (mt * BM >= n_e) return;
  __shared__ __align__(16) short As[BM * BK];
  __shared__ __align__(16) short Bs[BN * BK];
  const int t = threadIdx.x, lane = t & 63, wv = t >> 6;
  const int wm = wv >> 1, wn = wv & 1;
  const int srow = wv * 16 + (lane >> 2);
  const int kb = (lane & 3) * 8;
  const int obase = offs[e];
  int gr0 = mt * BM + srow;       gr0 = gr0 < n_e ? gr0 : n_e - 1;
  int gr1 = mt * BM + 64 + srow;  gr1 = gr1 < n_e ? gr1 : n_e - 1;
  const short* pa0 = h_buf + (size_t)(obase + gr0) * H_DIM + kb;
  const short* pa1 = h_buf + (size_t)(obase + gr1) * H_DIM + kb;
  const short* w2te = w2t + ((size_t)e * O_DIM + nt * BN) * H_DIM;
  const short* pb0 = w2te + (size_t)srow * H_DIM + kb;
  const short* pb1 = w2te + (size_t)(64 + srow) * H_DIM + kb;
  short* lA0 = As + wv * 16 * BK;
  short* lA1 = As + (64 + wv * 16) * BK;
  short* lB0 = Bs + wv * 16 * BK;
  short* lB1 = Bs + (64 + wv * 16) * BK;

  f32x4_t acc[4][4] = {};
  const int frow = lane & 15, kg = lane >> 4;

  for (int k0 = 0; k0 < H_DIM; k0 += BK) {
    g2l16(pa0 + k0, lA0);
    g2l16(pa1 + k0, lA1);
    g2l16(pb0 + k0, lB0);
    g2l16(pb1 + k0, lB1);
    __syncthreads();
    bf16x8_t af[4], bfr[4];
#pragma unroll
    for (int mi = 0; mi < 4; mi++)
      af[mi] = *(const bf16x8_t*)&As[(wm * 64 + mi * 16 + frow) * BK + kg * 8];
#pragma unroll
    for (int ni = 0; ni < 4; ni++)
      bfr[ni] = *(const bf16x8_t*)&Bs[(wn * 64 + ni * 16 + frow) * BK + kg * 8];
#pragma unroll
    for (int mi = 0; mi < 4; mi++)
#pragma unroll
      for (int ni = 0; ni < 4; ni++)
        acc[mi][ni] = __builtin_amdgcn_mfma_f32_16x16x32_bf16(af[mi], bfr[ni], acc[mi][ni], 0, 0, 0);
    __syncthreads();
  }
#pragma unroll
  for (int mi = 0; mi < 4; mi++) {
#pragma unroll
    for (int r = 0; r < 4; r++) {
      int row = wm * 64 + mi * 16 + kg * 4 + r;
      int m_local = mt * BM + row;
      if (m_local >= n_e) continue;
      float g = egate[e * B_DIM + m_local];
      size_t orow = (size_t)slotid[e * B_DIM + m_local] * O_DIM;
#pragma unroll
      for (int ni = 0; ni < 4; ni++) {
        int col = nt * BN + wn * 64 + ni * 16 + frow;
        out_buf[orow + col] = (acc[mi][ni][r] + b2[e * O_DIM + col]) * g;
      }
    }
  }
}

// ---------------- combine: y[b] = sum over 4 slots
__global__ __launch_bounds__(256) void combine_kernel(const float* __restrict__ out_buf,
                                                      float* __restrict__ y) {
  int idx = blockIdx.x * 256 + threadIdx.x;  // B*O/4 threads
  int b = idx >> 7;
  int o = (idx & 127) << 2;
  const float* base = out_buf + (size_t)b * K_TOP * O_DIM + o;
  float4 a0 = *(const float4*)(base);
  float4 a1 = *(const float4*)(base + O_DIM);
  float4 a2 = *(const float4*)(base + 2 * O_DIM);
  float4 a3 = *(const float4*)(base + 3 * O_DIM);
  float4 r;
  r.x = a0.x + a1.x + a2.x + a3.x;
  r.y = a0.y + a1.y + a2.y + a3.y;
  r.z = a0.z + a1.z + a2.z + a3.z;
  r.w = a0.w + a1.w + a2.w + a3.w;
  *(float4*)(y + (size_t)b * O_DIM + o) = r;
}

extern "C" void kernel_launch(void* const* d_in, const int* in_sizes, int n_in,
                              void* d_out, int out_size, void* d_ws, size_t ws_size,
                              hipStream_t stream) {
  (void)in_sizes; (void)n_in; (void)out_size; (void)ws_size;
  const float* query = (const float*)d_in[0];
  const float* x = (const float*)d_in[1];
  const float* wg = (const float*)d_in[2];
  const float* tg = (const float*)d_in[3];
  const float* W1 = (const float*)d_in[4];
  const float* b1 = (const float*)d_in[5];
  const float* W2 = (const float*)d_in[6];
  const float* b2 = (const float*)d_in[7];
  float* y = (float*)d_out;

  char* ws = (char*)d_ws;
  int* count = (int*)(ws + 0);                // 64 B
  float* imp = (float*)(ws + 64);             // 64 B
  int* offs = (int*)(ws + 128);               // 64 B
  int* rowlist = (int*)(ws + 256);            // 256 KB
  int* slotid = (int*)(ws + 262400);          // 256 KB
  float* egate = (float*)(ws + 524544);       // 256 KB
  int4* topk_e4 = (int4*)(ws + 786688);       // 64 KB
  float4* topk_g4 = (float4*)(ws + 852224);   // 64 KB
  float* wpack = (float*)(ws + 917760);       // 48 KB
  short* h_buf = (short*)(ws + 1048576);      // 32 MB bf16 [16384][H]  (live gemm1->gemm2)
  short* w2t = (short*)(ws + 34603008);       // 16 MB bf16 [E][O][H]   (live ->gemm2)
  // region A: dead after gemm1, overlaid by out_buf
  short* x_bf = (short*)(ws + 51380224);      // 4 MB  bf16 [4096][512]
  short* w1t = (short*)(ws + 55574528);       // 16 MB bf16 [E][H][D]
  float* out_buf = (float*)(ws + 51380224);   // 32 MB f32 [16384][O]   (overlays region A)

  prep_kernel<<<dim3(1072), 256, 0, stream>>>(x, wg, tg, x_bf, wpack);
  transpose_cvt<<<dim3(H_DIM / 64, D_DIM / 64, E_NUM), 256, 0, stream>>>(W1, w1t, D_DIM, H_DIM);
  transpose_cvt<<<dim3(O_DIM / 64, H_DIM / 64, E_NUM), 256, 0, stream>>>(W2, w2t, H_DIM, O_DIM);
  gating_kernel<<<dim3(B_DIM / 4), 256, 0, stream>>>(x, query, wpack, topk_e4, topk_g4);
  csr_kernel<<<dim3(E_NUM), 256, 0, stream>>>(topk_e4, topk_g4, count, imp,
                                              rowlist, slotid, egate);
  loss_offsets_kernel<<<1, 64, 0, stream>>>(count, imp, offs, y + (size_t)B_DIM * O_DIM);
  gemm1_kernel<<<dim3(H_DIM / BN, B_DIM / BM, E_NUM), 256, 0, stream>>>(
      x_bf, w1t, b1, count, offs, rowlist, h_buf);
  gemm2_kernel<<<dim3(O_DIM / BN, B_DIM / BM, E_NUM), 256, 0, stream>>>(
      h_buf, w2t, b2, count, offs, slotid, egate, out_buf);
  combine_kernel<<<dim3(B_DIM * O_DIM / 4 / 256), 256, 0, stream>>>(out_buf, y);
}

// Round 6
// 235.797 us; speedup vs baseline: 1.8605x; 1.0666x over previous
//
#include <hip/hip_runtime.h>

typedef short bf16x8_t __attribute__((ext_vector_type(8)));
typedef short bf16x4_t __attribute__((ext_vector_type(4)));
typedef float f32x4_t __attribute__((ext_vector_type(4)));

#define B_DIM 4096
#define Q_DIM 256
#define D_DIM 512
#define H_DIM 1024
#define O_DIM 512
#define E_NUM 16
#define K_TOP 4

#define BM 128
#define BN 128
#define BK 32

__device__ __forceinline__ short f2bf(float f) {
  unsigned int u = __float_as_uint(f);
  u += 0x7FFFu + ((u >> 16) & 1u);  // round-to-nearest-even
  return (short)(u >> 16);
}

// async global->LDS, 16B per lane; LDS dest wave-uniform base, lane i -> base+i*16
__device__ __forceinline__ void g2l16(const void* g, void* l) {
  __builtin_amdgcn_global_load_lds(
      (const __attribute__((address_space(1))) void*)(unsigned long long)(size_t)g,
      (__attribute__((address_space(3))) void*)(unsigned)(size_t)l, 16, 0, 0);
}

// ---------------- 64x64 transpose tile: src[R][C] f32 -> dst[C][R] bf16, vector stores
__device__ __forceinline__ void tr_tile(float (*tile)[65], const float* __restrict__ s,
                                        short* __restrict__ d, int R, int C, int r0, int c0,
                                        int t) {
#pragma unroll
  for (int i = 0; i < 16; i++) {
    int lin = i * 256 + t;
    int rr = lin >> 6, cc = lin & 63;
    tile[rr][cc] = s[(size_t)(r0 + rr) * C + (c0 + cc)];
  }
  __syncthreads();
#pragma unroll
  for (int i = 0; i < 2; i++) {
    int task = i * 256 + t;
    int cr = task >> 3, g = task & 7;  // per-wave: cr=lane>>3 (8 vals), g=lane&7 -> 2-way banks
    bf16x8_t v;
#pragma unroll
    for (int j = 0; j < 8; j++) v[j] = f2bf(tile[g * 8 + j][cr]);
    *(bf16x8_t*)(d + (size_t)(c0 + cr) * R + r0 + g * 8) = v;
  }
}

// ---------------- weights prep: W1 transpose (blk<2048), W2 transpose (<4096), wpack
__global__ __launch_bounds__(256) void weights_prep(
    const float* __restrict__ W1, const float* __restrict__ W2,
    const float* __restrict__ wg, const float* __restrict__ tg,
    short* __restrict__ w1t, short* __restrict__ w2t, float* __restrict__ wpack) {
  __shared__ float tile[64][65];
  const int blk = blockIdx.x, t = threadIdx.x;
  if (blk < 2048) {  // W1: [E][512][1024] -> w1t [E][1024][512]
    int e = blk >> 7, rem = blk & 127;
    int r0 = (rem >> 4) * 64, c0 = (rem & 15) * 64;
    tr_tile(tile, W1 + (size_t)e * D_DIM * H_DIM, w1t + (size_t)e * D_DIM * H_DIM,
            D_DIM, H_DIM, r0, c0, t);
  } else if (blk < 4096) {  // W2: [E][1024][512] -> w2t [E][512][1024]
    int b2 = blk - 2048;
    int e = b2 >> 7, rem = b2 & 127;
    int r0 = (rem >> 3) * 64, c0 = (rem & 7) * 64;
    tr_tile(tile, W2 + (size_t)e * H_DIM * O_DIM, w2t + (size_t)e * H_DIM * O_DIM,
            H_DIM, O_DIM, r0, c0, t);
  } else {  // wpack: 12288 elems over 48 blocks
    int lin = (blk - 4096) * 256 + t;
    if (lin < E_NUM * 768) {
      int e = lin / 768, r = lin % 768;
      wpack[lin] = (r < D_DIM) ? wg[r * E_NUM + e] : tg[(r - D_DIM) * E_NUM + e];
    }
  }
}

// ---------------- gating v7: 1 row/wave; also emits x_bf (bf16 copy of x). NO ATOMICS.
__global__ __launch_bounds__(256) void gating_kernel(
    const float* __restrict__ x, const float* __restrict__ query,
    const float* __restrict__ wpack,
    int4* __restrict__ topk_e4, float4* __restrict__ topk_g4, short* __restrict__ x_bf) {
  __shared__ __align__(16) float4 s_w[E_NUM * 192];  // 48 KB
  const int t = threadIdx.x, wv = t >> 6, lane = t & 63;
  const float4* wp4 = (const float4*)wpack;
#pragma unroll
  for (int i = 0; i < 12; i++) s_w[i * 256 + t] = wp4[i * 256 + t];
  __syncthreads();

  const int row = blockIdx.x * 4 + wv;
  const float4* xr = (const float4*)(x + (size_t)row * D_DIM);
  const float4* qr = (const float4*)(query + (size_t)row * Q_DIM);
  const float4 xv0 = xr[lane], xv1 = xr[64 + lane], qv = qr[lane];

  {  // emit bf16 x row (coalesced 8B stores)
    bf16x4_t v0, v1;
    v0[0] = f2bf(xv0.x); v0[1] = f2bf(xv0.y); v0[2] = f2bf(xv0.z); v0[3] = f2bf(xv0.w);
    v1[0] = f2bf(xv1.x); v1[1] = f2bf(xv1.y); v1[2] = f2bf(xv1.z); v1[3] = f2bf(xv1.w);
    short* xb = x_bf + (size_t)row * D_DIM;
    *(bf16x4_t*)(xb + lane * 4) = v0;
    *(bf16x4_t*)(xb + 256 + lane * 4) = v1;
  }

  float p[E_NUM];
#pragma unroll
  for (int e = 0; e < E_NUM; e++) {
    float4 w0 = s_w[e * 192 + lane];
    float4 w1 = s_w[e * 192 + 64 + lane];
    float4 wq = s_w[e * 192 + 128 + lane];
    p[e] = xv0.x * w0.x + xv0.y * w0.y + xv0.z * w0.z + xv0.w * w0.w +
           xv1.x * w1.x + xv1.y * w1.y + xv1.z * w1.z + xv1.w * w1.w +
           qv.x * wq.x + qv.y * wq.y + qv.z * wq.z + qv.w * wq.w;
  }
#pragma unroll
  for (int e = 0; e < E_NUM; e++) {
    p[e] += __shfl_xor(p[e], 16, 64);
    p[e] += __shfl_xor(p[e], 32, 64);
  }
  // fold e-dimension over lane bits 3..0; after this, lane l holds e = l & 15
#pragma unroll
  for (int s = 8; s >= 1; s >>= 1) {
    const bool take = (lane & s) != 0;
#pragma unroll
    for (int j = 0; j < s; j++) {
      float keep = take ? p[j + s] : p[j];
      float send = take ? p[j] : p[j + s];
      p[j] = keep + __shfl_xor(send, s, 64);
    }
  }
  const float logit = p[0];
  float v[E_NUM];
#pragma unroll
  for (int i = 0; i < E_NUM; i++) v[i] = __shfl(logit, i, 64);

  if (lane == 0) {
    int idx[K_TOP];
    float val[K_TOP];
    unsigned used = 0;
    for (int k = 0; k < K_TOP; k++) {  // strict '>' => lowest index wins ties
      float best = -3.4e38f;
      int bi = 0;
      for (int i = 0; i < E_NUM; i++)
        if (!(used & (1u << i)) && v[i] > best) { best = v[i]; bi = i; }
      used |= 1u << bi;
      idx[k] = bi;
      val[k] = best;
    }
    float mx = val[0];
    float ex[K_TOP], Z = 0.f;
    for (int k = 0; k < K_TOP; k++) { ex[k] = __expf(val[k] - mx); Z += ex[k]; }
    topk_e4[row] = make_int4(idx[0], idx[1], idx[2], idx[3]);
    topk_g4[row] = make_float4(ex[0] / Z, ex[1] / Z, ex[2] / Z, ex[3] / Z);
  }
}

// ---------------- CSR build: 1 block per expert, deterministic prefix-scan positions.
__global__ __launch_bounds__(256) void csr_kernel(
    const int4* __restrict__ topk_e4, const float4* __restrict__ topk_g4,
    int* __restrict__ count, float* __restrict__ imp_g,
    int* __restrict__ rowlist, int* __restrict__ slotid, float* __restrict__ egate) {
  const int e = blockIdx.x, t = threadIdx.x;
  __shared__ int s_cnt[256];
  __shared__ float s_gs[64];
  int c = 0;
  float gs = 0.f;
#pragma unroll 4
  for (int i = 0; i < 16; i++) {
    int row = t * 16 + i;
    int4 v = topk_e4[row];
    float4 g = topk_g4[row];
    if (v.x == e) { c++; gs += g.x; }
    if (v.y == e) { c++; gs += g.y; }
    if (v.z == e) { c++; gs += g.z; }
    if (v.w == e) { c++; gs += g.w; }
  }
  s_cnt[t] = c;
  float gw = gs;
  for (int off = 32; off >= 1; off >>= 1) gw += __shfl_down(gw, off, 64);
  if ((t & 63) == 0) s_gs[t >> 6] = gw;
  __syncthreads();
  for (int off = 1; off < 256; off <<= 1) {
    int vv = (t >= off) ? s_cnt[t - off] : 0;
    __syncthreads();
    s_cnt[t] += vv;
    __syncthreads();
  }
  int pos = s_cnt[t] - c;
#pragma unroll 4
  for (int i = 0; i < 16; i++) {
    int row = t * 16 + i;
    int4 v = topk_e4[row];
    float4 g = topk_g4[row];
    int ve[4] = {v.x, v.y, v.z, v.w};
    float vg[4] = {g.x, g.y, g.z, g.w};
#pragma unroll
    for (int k = 0; k < K_TOP; k++) {
      if (ve[k] == e) {
        rowlist[e * B_DIM + pos] = row;
        slotid[e * B_DIM + pos] = row * K_TOP + k;
        egate[e * B_DIM + pos] = vg[k];
        pos++;
      }
    }
  }
  if (t == 0) {
    count[e] = s_cnt[255];
    imp_g[e] = s_gs[0] + s_gs[1] + s_gs[2] + s_gs[3];
  }
}

// ---------------- loss (cv^2 ddof=1) + per-expert prefix offsets
__global__ __launch_bounds__(64) void loss_offsets_kernel(
    const int* __restrict__ count, const float* __restrict__ imp_g,
    int* __restrict__ offs, float* __restrict__ out_loss) {
  if (threadIdx.x == 0) {
    float mi = 0.f, ml = 0.f;
    for (int i = 0; i < E_NUM; i++) { mi += imp_g[i]; ml += (float)count[i]; }
    mi /= (float)E_NUM;
    ml /= (float)E_NUM;
    float vi = 0.f, vl = 0.f;
    for (int i = 0; i < E_NUM; i++) {
      float di = imp_g[i] - mi;
      vi += di * di;
      float dl = (float)count[i] - ml;
      vl += dl * dl;
    }
    vi /= (float)(E_NUM - 1);
    vl /= (float)(E_NUM - 1);
    out_loss[0] = 0.01f * (vi / (mi * mi + 1e-10f) + vl / (ml * ml + 1e-10f));
    int run = 0;
    for (int i = 0; i < E_NUM; i++) { offs[i] = run; run += count[i]; }
  }
}

// ---------------- GEMM1: h[entry] = relu(x[row] @ W1[e] + b1[e]), bf16 out
// flat grid 4096, XCD-swizzled: 32 mt-blocks of one (e,nt) share B-tile on one XCD.
__global__ __launch_bounds__(256) void gemm1_kernel(
    const short* __restrict__ x_bf, const short* __restrict__ w1t,
    const float* __restrict__ b1, const int* __restrict__ count,
    const int* __restrict__ offs, const int* __restrict__ rowlist,
    short* __restrict__ h_buf) {
  const int flat = blockIdx.x;
  const int xcd = flat & 7, j = flat >> 3;      // j 0..511
  const int mt = j & 31, gidx = j >> 5;         // gidx 0..15
  const int group = xcd * 16 + gidx;
  const int e = group >> 3, nt = group & 7;
  const int n_e = count[e];
  if (mt * BM >= n_e) return;
  __shared__ __align__(16) short As[BM * BK];
  __shared__ __align__(16) short Bs[BN * BK];
  const int t = threadIdx.x, lane = t & 63, wv = t >> 6;
  const int wm = wv >> 1, wn = wv & 1;
  const int srow = wv * 16 + (lane >> 2);  // staging row 0..63
  const int kb = (lane & 3) * 8;           // bf16 elems within 32-elem k-slice
  int gr0 = mt * BM + srow;       gr0 = gr0 < n_e ? gr0 : n_e - 1;
  int gr1 = mt * BM + 64 + srow;  gr1 = gr1 < n_e ? gr1 : n_e - 1;
  const short* pa0 = x_bf + (size_t)rowlist[e * B_DIM + gr0] * D_DIM + kb;
  const short* pa1 = x_bf + (size_t)rowlist[e * B_DIM + gr1] * D_DIM + kb;
  const short* w1te = w1t + ((size_t)e * H_DIM + nt * BN) * D_DIM;
  const short* pb0 = w1te + (size_t)srow * D_DIM + kb;
  const short* pb1 = w1te + (size_t)(64 + srow) * D_DIM + kb;
  short* lA0 = As + wv * 16 * BK;
  short* lA1 = As + (64 + wv * 16) * BK;
  short* lB0 = Bs + wv * 16 * BK;
  short* lB1 = Bs + (64 + wv * 16) * BK;

  f32x4_t acc[4][4] = {};
  const int frow = lane & 15, kg = lane >> 4;

  for (int k0 = 0; k0 < D_DIM; k0 += BK) {
    g2l16(pa0 + k0, lA0);
    g2l16(pa1 + k0, lA1);
    g2l16(pb0 + k0, lB0);
    g2l16(pb1 + k0, lB1);
    __syncthreads();
    bf16x8_t af[4], bfr[4];
#pragma unroll
    for (int mi = 0; mi < 4; mi++)
      af[mi] = *(const bf16x8_t*)&As[(wm * 64 + mi * 16 + frow) * BK + kg * 8];
#pragma unroll
    for (int ni = 0; ni < 4; ni++)
      bfr[ni] = *(const bf16x8_t*)&Bs[(wn * 64 + ni * 16 + frow) * BK + kg * 8];
#pragma unroll
    for (int mi = 0; mi < 4; mi++)
#pragma unroll
      for (int ni = 0; ni < 4; ni++)
        acc[mi][ni] = __builtin_amdgcn_mfma_f32_16x16x32_bf16(af[mi], bfr[ni], acc[mi][ni], 0, 0, 0);
    __syncthreads();
  }
  const int obase = offs[e];
#pragma unroll
  for (int mi = 0; mi < 4; mi++) {
#pragma unroll
    for (int r = 0; r < 4; r++) {
      int row = wm * 64 + mi * 16 + kg * 4 + r;
      int m_local = mt * BM + row;
      if (m_local >= n_e) continue;
      size_t hrow = (size_t)(obase + m_local) * H_DIM;
#pragma unroll
      for (int ni = 0; ni < 4; ni++) {
        int col = nt * BN + wn * 64 + ni * 16 + frow;
        float vv = acc[mi][ni][r] + b1[e * H_DIM + col];
        h_buf[hrow + col] = f2bf(vv > 0.f ? vv : 0.f);
      }
    }
  }
}

// ---------------- GEMM2: out_buf[slot] = (h[entry] @ W2[e] + b2[e]) * gate
// flat grid 2048, XCD-swizzled: 4 nt-blocks of one (e,mt) share A-tile on one XCD.
__global__ __launch_bounds__(256) void gemm2_kernel(
    const short* __restrict__ h_buf, const short* __restrict__ w2t,
    const float* __restrict__ b2, const int* __restrict__ count,
    const int* __restrict__ offs, const int* __restrict__ slotid,
    const float* __restrict__ egate, float* __restrict__ out_buf) {
  const int flat = blockIdx.x;
  const int xcd = flat & 7, j = flat >> 3;  // j 0..255
  const int nt = j & 3, gidx = j >> 2;      // gidx 0..63
  const int group = xcd * 64 + gidx;
  const int e = group >> 5, mt = group & 31;
  const int n_e = count[e];
  if (mt * BM >= n_e) return;
  __shared__ __align__(16) short As[BM * BK];
  __shared__ __align__(16) short Bs[BN * BK];
  const int t = threadIdx.x, lane = t & 63, wv = t >> 6;
  const int wm = wv >> 1, wn = wv & 1;
  const int srow = wv * 16 + (lane >> 2);
  const int kb = (lane & 3) * 8;
  const int obase = offs[e];
  int gr0 = mt * BM + srow;       gr0 = gr0 < n_e ? gr0 : n_e - 1;
  int gr1 = mt * BM + 64 + srow;  gr1 = gr1 < n_e ? gr1 : n_e - 1;
  const short* pa0 = h_buf + (size_t)(obase + gr0) * H_DIM + kb;
  const short* pa1 = h_buf + (size_t)(obase + gr1) * H_DIM + kb;
  const short* w2te = w2t + ((size_t)e * O_DIM + nt * BN) * H_DIM;
  const short* pb0 = w2te + (size_t)srow * H_DIM + kb;
  const short* pb1 = w2te + (size_t)(64 + srow) * H_DIM + kb;
  short* lA0 = As + wv * 16 * BK;
  short* lA1 = As + (64 + wv * 16) * BK;
  short* lB0 = Bs + wv * 16 * BK;
  short* lB1 = Bs + (64 + wv * 16) * BK;

  f32x4_t acc[4][4] = {};
  const int frow = lane & 15, kg = lane >> 4;

  for (int k0 = 0; k0 < H_DIM; k0 += BK) {
    g2l16(pa0 + k0, lA0);
    g2l16(pa1 + k0, lA1);
    g2l16(pb0 + k0, lB0);
    g2l16(pb1 + k0, lB1);
    __syncthreads();
    bf16x8_t af[4], bfr[4];
#pragma unroll
    for (int mi = 0; mi < 4; mi++)
      af[mi] = *(const bf16x8_t*)&As[(wm * 64 + mi * 16 + frow) * BK + kg * 8];
#pragma unroll
    for (int ni = 0; ni < 4; ni++)
      bfr[ni] = *(const bf16x8_t*)&Bs[(wn * 64 + ni * 16 + frow) * BK + kg * 8];
#pragma unroll
    for (int mi = 0; mi < 4; mi++)
#pragma unroll
      for (int ni = 0; ni < 4; ni++)
        acc[mi][ni] = __builtin_amdgcn_mfma_f32_16x16x32_bf16(af[mi], bfr[ni], acc[mi][ni], 0, 0, 0);
    __syncthreads();
  }
#pragma unroll
  for (int mi = 0; mi < 4; mi++) {
#pragma unroll
    for (int r = 0; r < 4; r++) {
      int row = wm * 64 + mi * 16 + kg * 4 + r;
      int m_local = mt * BM + row;
      if (m_local >= n_e) continue;
      float g = egate[e * B_DIM + m_local];
      size_t orow = (size_t)slotid[e * B_DIM + m_local] * O_DIM;
#pragma unroll
      for (int ni = 0; ni < 4; ni++) {
        int col = nt * BN + wn * 64 + ni * 16 + frow;
        out_buf[orow + col] = (acc[mi][ni][r] + b2[e * O_DIM + col]) * g;
      }
    }
  }
}

// ---------------- combine: y[b] = sum over 4 slots
__global__ __launch_bounds__(256) void combine_kernel(const float* __restrict__ out_buf,
                                                      float* __restrict__ y) {
  int idx = blockIdx.x * 256 + threadIdx.x;  // B*O/4 threads
  int b = idx >> 7;
  int o = (idx & 127) << 2;
  const float* base = out_buf + (size_t)b * K_TOP * O_DIM + o;
  float4 a0 = *(const float4*)(base);
  float4 a1 = *(const float4*)(base + O_DIM);
  float4 a2 = *(const float4*)(base + 2 * O_DIM);
  float4 a3 = *(const float4*)(base + 3 * O_DIM);
  float4 r;
  r.x = a0.x + a1.x + a2.x + a3.x;
  r.y = a0.y + a1.y + a2.y + a3.y;
  r.z = a0.z + a1.z + a2.z + a3.z;
  r.w = a0.w + a1.w + a2.w + a3.w;
  *(float4*)(y + (size_t)b * O_DIM + o) = r;
}

extern "C" void kernel_launch(void* const* d_in, const int* in_sizes, int n_in,
                              void* d_out, int out_size, void* d_ws, size_t ws_size,
                              hipStream_t stream) {
  (void)in_sizes; (void)n_in; (void)out_size; (void)ws_size;
  const float* query = (const float*)d_in[0];
  const float* x = (const float*)d_in[1];
  const float* wg = (const float*)d_in[2];
  const float* tg = (const float*)d_in[3];
  const float* W1 = (const float*)d_in[4];
  const float* b1 = (const float*)d_in[5];
  const float* W2 = (const float*)d_in[6];
  const float* b2 = (const float*)d_in[7];
  float* y = (float*)d_out;

  char* ws = (char*)d_ws;
  int* count = (int*)(ws + 0);                // 64 B
  float* imp = (float*)(ws + 64);             // 64 B
  int* offs = (int*)(ws + 128);               // 64 B
  int* rowlist = (int*)(ws + 256);            // 256 KB
  int* slotid = (int*)(ws + 262400);          // 256 KB
  float* egate = (float*)(ws + 524544);       // 256 KB
  int4* topk_e4 = (int4*)(ws + 786688);       // 64 KB
  float4* topk_g4 = (float4*)(ws + 852224);   // 64 KB
  float* wpack = (float*)(ws + 917760);       // 48 KB
  short* h_buf = (short*)(ws + 1048576);      // 32 MB bf16 [16384][H]  (live gemm1->gemm2)
  short* w2t = (short*)(ws + 34603008);       // 16 MB bf16 [E][O][H]   (live ->gemm2)
  // region A: dead after gemm1, overlaid by out_buf
  short* x_bf = (short*)(ws + 51380224);      // 4 MB  bf16 [4096][512]
  short* w1t = (short*)(ws + 55574528);       // 16 MB bf16 [E][H][D]
  float* out_buf = (float*)(ws + 51380224);   // 32 MB f32 [16384][O]   (overlays region A)

  weights_prep<<<dim3(4144), 256, 0, stream>>>(W1, W2, wg, tg, w1t, w2t, wpack);
  gating_kernel<<<dim3(B_DIM / 4), 256, 0, stream>>>(x, query, wpack, topk_e4, topk_g4, x_bf);
  csr_kernel<<<dim3(E_NUM), 256, 0, stream>>>(topk_e4, topk_g4, count, imp,
                                              rowlist, slotid, egate);
  loss_offsets_kernel<<<1, 64, 0, stream>>>(count, imp, offs, y + (size_t)B_DIM * O_DIM);
  gemm1_kernel<<<dim3(4096), 256, 0, stream>>>(x_bf, w1t, b1, count, offs, rowlist, h_buf);
  gemm2_kernel<<<dim3(2048), 256, 0, stream>>>(h_buf, w2t, b2, count, offs, slotid, egate,
                                               out_buf);
  combine_kernel<<<dim3(B_DIM * O_DIM / 4 / 256), 256, 0, stream>>>(out_buf, y);
}